// Round 1
// baseline (71.671 us; speedup 1.0000x reference)
//
#include <hip/hip_runtime.h>
#include <math.h>

#define N_PTS 16384
#define PBLK 1024              // p points per block in k_nn (256 thr x 4)
#define GCHUNK 512             // g points per block in k_nn
#define NPBLK (N_PTS / PBLK)   // 16
#define NGCHUNK (N_PTS / GCHUNK) // 32

// Monotone float->u32 encoding so unsigned min == float min (finite values).
__device__ __forceinline__ unsigned enc_f32(float f) {
    unsigned b = __float_as_uint(f);
    return (b & 0x80000000u) ? ~b : (b | 0x80000000u);
}
__device__ __forceinline__ float dec_f32(unsigned k) {
    unsigned b = (k & 0x80000000u) ? (k & 0x7fffffffu) : ~k;
    return __uint_as_float(b);
}

// K1: p = R*m + t; stage (x,y,z,|.|^2) for both p and g; init min keys.
__global__ __launch_bounds__(256) void k_transform(
        const float* __restrict__ R, const float* __restrict__ t,
        const float* __restrict__ m, const float* __restrict__ g,
        float4* __restrict__ pws, float4* __restrict__ gws,
        unsigned* __restrict__ keys) {
    int n = blockIdx.x * 256 + threadIdx.x;
    if (n >= N_PTS) return;
    float mx = m[3*n+0], my = m[3*n+1], mz = m[3*n+2];
    float px = fmaf(R[0], mx, fmaf(R[1], my, R[2]*mz)) + t[0];
    float py = fmaf(R[3], mx, fmaf(R[4], my, R[5]*mz)) + t[1];
    float pz = fmaf(R[6], mx, fmaf(R[7], my, R[8]*mz)) + t[2];
    pws[n] = make_float4(px, py, pz, fmaf(px,px,fmaf(py,py,pz*pz)));
    float gx = g[3*n+0], gy = g[3*n+1], gz = g[3*n+2];
    gws[n] = make_float4(gx, gy, gz, fmaf(gx,gx,fmaf(gy,gy,gz*gz)));
    keys[n] = 0xFFFFFFFFu;
}

// K2: brute-force NN. Each thread owns 4 p points; loops over a 512-g chunk.
// g load is wave-uniform -> scalar loads; 5 VALU ops per (p,g) pair.
__global__ __launch_bounds__(256) void k_nn(
        const float4* __restrict__ pws, const float4* __restrict__ gws,
        unsigned* __restrict__ keys) {
    const int tid = threadIdx.x;
    const int pbase = blockIdx.x * PBLK;
    const int g0 = blockIdx.y * GCHUNK;

    float px[4], py[4], pz[4], sm[4];
    #pragma unroll
    for (int k = 0; k < 4; ++k) {
        float4 p = pws[pbase + k*256 + tid];
        px[k] = p.x; py[k] = p.y; pz[k] = p.z;
        sm[k] = 3.4e38f;
    }

    #pragma unroll 4
    for (int g = g0; g < g0 + GCHUNK; ++g) {
        float4 gv = gws[g];   // uniform across wave
        #pragma unroll
        for (int k = 0; k < 4; ++k) {
            float d = fmaf(px[k], gv.x, fmaf(py[k], gv.y, pz[k]*gv.z));
            float s = fmaf(-2.0f, d, gv.w);   // |g|^2 - 2 p.g
            sm[k] = fminf(sm[k], s);
        }
    }

    #pragma unroll
    for (int k = 0; k < 4; ++k)
        atomicMin(&keys[pbase + k*256 + tid], enc_f32(sm[k]));
}

// K3: dis = sqrt(max(|p|^2 + s_min, 0)); block-reduce to one partial sum.
__global__ __launch_bounds__(256) void k_finalize(
        const float4* __restrict__ pws, const float* __restrict__ g,
        const unsigned* __restrict__ keys, const int* __restrict__ midx,
        float* __restrict__ partials) {
    const int tid = threadIdx.x;
    const int pbase = blockIdx.x * PBLK;
    const bool sym = (midx[0] == 0);
    float acc = 0.f;
    #pragma unroll
    for (int k = 0; k < 4; ++k) {
        int n = pbase + k*256 + tid;
        float4 p = pws[n];
        float dis;
        if (sym) {
            float s = dec_f32(keys[n]);
            dis = sqrtf(fmaxf(p.w + s, 0.f));
        } else {
            float dx = p.x - g[3*n+0], dy = p.y - g[3*n+1], dz = p.z - g[3*n+2];
            dis = sqrtf(fmaf(dx,dx,fmaf(dy,dy,dz*dz)));
        }
        acc += dis;
    }
    #pragma unroll
    for (int off = 32; off > 0; off >>= 1) acc += __shfl_down(acc, off, 64);
    __shared__ float sred[4];
    if ((tid & 63) == 0) sred[tid >> 6] = acc;
    __syncthreads();
    if (tid == 0) partials[blockIdx.x] = (sred[0] + sred[1]) + (sred[2] + sred[3]);
}

// K4: final reduction of 16 partials -> mean.
__global__ void k_final(const float* __restrict__ partials, float* __restrict__ out) {
    float v = (threadIdx.x < NPBLK) ? partials[threadIdx.x] : 0.f;
    #pragma unroll
    for (int off = 8; off > 0; off >>= 1) v += __shfl_down(v, off, 64);
    if (threadIdx.x == 0) out[0] = v / (float)N_PTS;
}

extern "C" void kernel_launch(void* const* d_in, const int* in_sizes, int n_in,
                              void* d_out, int out_size, void* d_ws, size_t ws_size,
                              hipStream_t stream) {
    const float* R   = (const float*)d_in[0];
    const float* t   = (const float*)d_in[1];
    const float* m   = (const float*)d_in[2];
    const float* g   = (const float*)d_in[3];
    const int* midx  = (const int*)d_in[4];

    char* ws = (char*)d_ws;
    float4*   pws      = (float4*)(ws + 0);
    float4*   gws      = (float4*)(ws + 262144);
    unsigned* keys     = (unsigned*)(ws + 524288);
    float*    partials = (float*)(ws + 589824);
    float*    out      = (float*)d_out;

    k_transform<<<dim3(N_PTS/256), dim3(256), 0, stream>>>(R, t, m, g, pws, gws, keys);
    k_nn<<<dim3(NPBLK, NGCHUNK), dim3(256), 0, stream>>>(pws, gws, keys);
    k_finalize<<<dim3(NPBLK), dim3(256), 0, stream>>>(pws, g, keys, midx, partials);
    k_final<<<dim3(1), dim3(64), 0, stream>>>(partials, out);
}

// Round 2
// 45.139 us; speedup vs baseline: 1.5878x; 1.5878x over previous
//
#include <hip/hip_runtime.h>
#include <math.h>

#define N_PTS 16384
#define PBLK 512                  // p points per k_nn block (256 thr x 2)
#define GCHUNK 256                // g points per k_nn block
#define NPBLK (N_PTS / PBLK)      // 32
#define NGCHUNK (N_PTS / GCHUNK)  // 64

// Monotone float->u32 encoding so unsigned min == float min (finite values).
__device__ __forceinline__ unsigned enc_f32(float f) {
    unsigned b = __float_as_uint(f);
    return (b & 0x80000000u) ? ~b : (b | 0x80000000u);
}
__device__ __forceinline__ float dec_f32(unsigned k) {
    unsigned b = (k & 0x80000000u) ? (k & 0x7fffffffu) : ~k;
    return __uint_as_float(b);
}

// K1: p = R*m + t; stage (-2x,-2y,-2z,|p|^2) for p and (x,y,z,|g|^2) for g.
__global__ __launch_bounds__(256) void k_transform(
        const float* __restrict__ R, const float* __restrict__ t,
        const float* __restrict__ m, const float* __restrict__ g,
        float4* __restrict__ pws, float4* __restrict__ gws,
        unsigned* __restrict__ keys, int init_keys) {
    int n = blockIdx.x * 256 + threadIdx.x;
    if (n >= N_PTS) return;
    float mx = m[3*n+0], my = m[3*n+1], mz = m[3*n+2];
    float px = fmaf(R[0], mx, fmaf(R[1], my, R[2]*mz)) + t[0];
    float py = fmaf(R[3], mx, fmaf(R[4], my, R[5]*mz)) + t[1];
    float pz = fmaf(R[6], mx, fmaf(R[7], my, R[8]*mz)) + t[2];
    float pp = fmaf(px,px,fmaf(py,py,pz*pz));
    pws[n] = make_float4(-2.f*px, -2.f*py, -2.f*pz, pp);
    float gx = g[3*n+0], gy = g[3*n+1], gz = g[3*n+2];
    gws[n] = make_float4(gx, gy, gz, fmaf(gx,gx,fmaf(gy,gy,gz*gz)));
    if (init_keys) keys[n] = 0xFFFFFFFFu;
}

// K2: brute-force NN over one 256-g chunk staged in LDS.
// sm = min over g of (|g|^2 - 2 p.g); true d2 = |p|^2 + sm (added in finalize).
template<bool ATOMIC>
__global__ __launch_bounds__(256, 8) void k_nn(
        const float4* __restrict__ pws, const float4* __restrict__ gws,
        float* __restrict__ partial /* or unsigned keys when ATOMIC */) {
    __shared__ float4 sg[GCHUNK];
    const int tid = threadIdx.x;
    const int pbase = blockIdx.x * PBLK;
    const int g0 = blockIdx.y * GCHUNK;

    sg[tid] = gws[g0 + tid];                 // 4KB stage, one float4/thread
    float4 p0 = pws[pbase + tid];            // (-2x,-2y,-2z,pp)
    float4 p1 = pws[pbase + 256 + tid];
    __syncthreads();

    float sm0 = 3.4e38f, sm1 = 3.4e38f;
    #pragma unroll 8
    for (int gi = 0; gi < GCHUNK; ++gi) {
        float4 gv = sg[gi];                  // uniform addr -> broadcast
        float s0 = fmaf(p0.x, gv.x, fmaf(p0.y, gv.y, fmaf(p0.z, gv.z, gv.w)));
        float s1 = fmaf(p1.x, gv.x, fmaf(p1.y, gv.y, fmaf(p1.z, gv.z, gv.w)));
        sm0 = fminf(sm0, s0);
        sm1 = fminf(sm1, s1);
    }

    if (ATOMIC) {
        unsigned* keys = (unsigned*)partial;
        atomicMin(&keys[pbase + tid],       enc_f32(sm0));
        atomicMin(&keys[pbase + 256 + tid], enc_f32(sm1));
    } else {
        partial[blockIdx.y * N_PTS + pbase + tid]       = sm0;
        partial[blockIdx.y * N_PTS + pbase + 256 + tid] = sm1;
    }
}

// K3: per-point min over chunks, d2 = pp + sm, dis = sqrt, block-sum.
template<bool ATOMIC>
__global__ __launch_bounds__(256) void k_finalize(
        const float4* __restrict__ pws, const float* __restrict__ g,
        const float* __restrict__ partial, const int* __restrict__ midx,
        float* __restrict__ psum) {
    const int tid = threadIdx.x;
    const int n = blockIdx.x * 256 + tid;
    const bool sym = (midx[0] == 0);
    float4 p = pws[n];
    float dis;
    if (sym) {
        float sm;
        if (ATOMIC) {
            sm = dec_f32(((const unsigned*)partial)[n]);
        } else {
            sm = 3.4e38f;
            #pragma unroll 8
            for (int c = 0; c < NGCHUNK; ++c)
                sm = fminf(sm, partial[c * N_PTS + n]);
        }
        dis = sqrtf(fmaxf(p.w + sm, 0.f));
    } else {
        float px = -0.5f*p.x, py = -0.5f*p.y, pz = -0.5f*p.z;
        float dx = px - g[3*n+0], dy = py - g[3*n+1], dz = pz - g[3*n+2];
        dis = sqrtf(fmaf(dx,dx,fmaf(dy,dy,dz*dz)));
    }
    float acc = dis;
    #pragma unroll
    for (int off = 32; off > 0; off >>= 1) acc += __shfl_down(acc, off, 64);
    __shared__ float sred[4];
    if ((tid & 63) == 0) sred[tid >> 6] = acc;
    __syncthreads();
    if (tid == 0) psum[blockIdx.x] = (sred[0] + sred[1]) + (sred[2] + sred[3]);
}

// K4: final reduction of 64 partial sums -> mean.
__global__ void k_final(const float* __restrict__ psum, float* __restrict__ out) {
    float v = psum[threadIdx.x];
    #pragma unroll
    for (int off = 32; off > 0; off >>= 1) v += __shfl_down(v, off, 64);
    if (threadIdx.x == 0) out[0] = v / (float)N_PTS;
}

extern "C" void kernel_launch(void* const* d_in, const int* in_sizes, int n_in,
                              void* d_out, int out_size, void* d_ws, size_t ws_size,
                              hipStream_t stream) {
    const float* R   = (const float*)d_in[0];
    const float* t   = (const float*)d_in[1];
    const float* m   = (const float*)d_in[2];
    const float* g   = (const float*)d_in[3];
    const int* midx  = (const int*)d_in[4];

    char* ws = (char*)d_ws;
    float4* pws     = (float4*)(ws + 0);
    float4* gws     = (float4*)(ws + 262144);
    float*  partial = (float*)(ws + 524288);   // 4MB partials OR 64KB keys
    float*  out     = (float*)d_out;

    const size_t partial_bytes = (size_t)NGCHUNK * N_PTS * 4;   // 4 MB
    const bool use_partial = ws_size >= 524288 + partial_bytes + 1024;
    float* psum = use_partial ? (float*)(ws + 524288 + partial_bytes)
                              : (float*)(ws + 524288 + 65536);

    k_transform<<<dim3(N_PTS/256), dim3(256), 0, stream>>>(
        R, t, m, g, pws, gws, (unsigned*)partial, use_partial ? 0 : 1);

    if (use_partial) {
        k_nn<false><<<dim3(NPBLK, NGCHUNK), dim3(256), 0, stream>>>(pws, gws, partial);
        k_finalize<false><<<dim3(N_PTS/256), dim3(256), 0, stream>>>(pws, g, partial, midx, psum);
    } else {
        k_nn<true><<<dim3(NPBLK, NGCHUNK), dim3(256), 0, stream>>>(pws, gws, partial);
        k_finalize<true><<<dim3(N_PTS/256), dim3(256), 0, stream>>>(pws, g, partial, midx, psum);
    }
    k_final<<<dim3(1), dim3(64), 0, stream>>>(psum, out);
}

// Round 3
// 42.185 us; speedup vs baseline: 1.6990x; 1.0700x over previous
//
#include <hip/hip_runtime.h>
#include <math.h>

#define N_PTS 16384
#define PBLK 512                  // p points per k_nn block (256 thr x 2)
#define GCHUNK 256                // g points per k_nn block
#define NPBLK (N_PTS / PBLK)      // 32
#define NGCHUNK (N_PTS / GCHUNK)  // 64

// Monotone float->u32 encoding so unsigned min == float min (finite values).
__device__ __forceinline__ unsigned enc_f32(float f) {
    unsigned b = __float_as_uint(f);
    return (b & 0x80000000u) ? ~b : (b | 0x80000000u);
}
__device__ __forceinline__ float dec_f32(unsigned k) {
    unsigned b = (k & 0x80000000u) ? (k & 0x7fffffffu) : ~k;
    return __uint_as_float(b);
}

// Fallback-only: init atomic min keys.
__global__ __launch_bounds__(256) void k_init(unsigned* __restrict__ keys) {
    keys[blockIdx.x * 256 + threadIdx.x] = 0xFFFFFFFFu;
}

// Fused transform + brute-force NN.
// Each block: stages its 256-g chunk (x,y,z,|g|^2) into LDS from raw gt,
// computes its 512 p = R*m+t (held as (-2px,-2py,-2pz) + pp), then
// min over chunk of (|g|^2 - 2 p.g); writes min-d2 partial (pp folded in).
template<bool ATOMIC>
__global__ __launch_bounds__(256, 8) void k_nn(
        const float* __restrict__ R, const float* __restrict__ t,
        const float* __restrict__ m, const float* __restrict__ g,
        float* __restrict__ partial /* or unsigned keys when ATOMIC */) {
    __shared__ float4 sg[GCHUNK];
    const int tid = threadIdx.x;
    const int pbase = blockIdx.x * PBLK;
    const int g0 = blockIdx.y * GCHUNK;

    // stage g chunk -> LDS
    {
        int n = g0 + tid;
        float gx = g[3*n+0], gy = g[3*n+1], gz = g[3*n+2];
        sg[tid] = make_float4(gx, gy, gz, fmaf(gx,gx,fmaf(gy,gy,gz*gz)));
    }

    // uniform rotation/translation (scalar loads)
    const float r0=R[0], r1=R[1], r2=R[2], r3=R[3], r4=R[4],
                r5=R[5], r6=R[6], r7=R[7], r8=R[8];
    const float t0=t[0], t1=t[1], t2=t[2];

    // 2 p points per thread, -2 folded into coords
    float p0x,p0y,p0z,pp0, p1x,p1y,p1z,pp1;
    {
        int n = pbase + tid;
        float mx=m[3*n+0], my=m[3*n+1], mz=m[3*n+2];
        float px = fmaf(r0,mx,fmaf(r1,my,r2*mz)) + t0;
        float py = fmaf(r3,mx,fmaf(r4,my,r5*mz)) + t1;
        float pz = fmaf(r6,mx,fmaf(r7,my,r8*mz)) + t2;
        pp0 = fmaf(px,px,fmaf(py,py,pz*pz));
        p0x = -2.f*px; p0y = -2.f*py; p0z = -2.f*pz;
    }
    {
        int n = pbase + 256 + tid;
        float mx=m[3*n+0], my=m[3*n+1], mz=m[3*n+2];
        float px = fmaf(r0,mx,fmaf(r1,my,r2*mz)) + t0;
        float py = fmaf(r3,mx,fmaf(r4,my,r5*mz)) + t1;
        float pz = fmaf(r6,mx,fmaf(r7,my,r8*mz)) + t2;
        pp1 = fmaf(px,px,fmaf(py,py,pz*pz));
        p1x = -2.f*px; p1y = -2.f*py; p1z = -2.f*pz;
    }
    __syncthreads();

    float sm0 = 3.4e38f, sm1 = 3.4e38f;
    #pragma unroll 8
    for (int gi = 0; gi < GCHUNK; gi += 2) {
        float4 a = sg[gi];       // uniform addr -> broadcast, no conflicts
        float4 b = sg[gi+1];
        float s0a = fmaf(p0x, a.x, fmaf(p0y, a.y, fmaf(p0z, a.z, a.w)));
        float s0b = fmaf(p0x, b.x, fmaf(p0y, b.y, fmaf(p0z, b.z, b.w)));
        float s1a = fmaf(p1x, a.x, fmaf(p1y, a.y, fmaf(p1z, a.z, a.w)));
        float s1b = fmaf(p1x, b.x, fmaf(p1y, b.y, fmaf(p1z, b.z, b.w)));
        sm0 = fminf(sm0, fminf(s0a, s0b));   // -> v_min3_f32
        sm1 = fminf(sm1, fminf(s1a, s1b));
    }
    sm0 += pp0;   // min d2 for this chunk
    sm1 += pp1;

    if (ATOMIC) {
        unsigned* keys = (unsigned*)partial;
        atomicMin(&keys[pbase + tid],       enc_f32(sm0));
        atomicMin(&keys[pbase + 256 + tid], enc_f32(sm1));
    } else {
        partial[blockIdx.y * N_PTS + pbase + tid]       = sm0;
        partial[blockIdx.y * N_PTS + pbase + 256 + tid] = sm1;
    }
}

// Per-point min over chunks -> sqrt -> block partial sum.
template<bool ATOMIC>
__global__ __launch_bounds__(256) void k_finalize(
        const float* __restrict__ R, const float* __restrict__ t,
        const float* __restrict__ m, const float* __restrict__ g,
        const float* __restrict__ partial, const int* __restrict__ midx,
        float* __restrict__ psum) {
    const int tid = threadIdx.x;
    const int n = blockIdx.x * 256 + tid;
    const bool sym = (midx[0] == 0);
    float dis;
    if (sym) {
        float d2;
        if (ATOMIC) {
            d2 = dec_f32(((const unsigned*)partial)[n]);
        } else {
            d2 = 3.4e38f;
            #pragma unroll 8
            for (int c = 0; c < NGCHUNK; ++c)
                d2 = fminf(d2, partial[c * N_PTS + n]);
        }
        dis = sqrtf(fmaxf(d2, 0.f));
    } else {
        float mx=m[3*n+0], my=m[3*n+1], mz=m[3*n+2];
        float px = fmaf(R[0],mx,fmaf(R[1],my,R[2]*mz)) + t[0] - g[3*n+0];
        float py = fmaf(R[3],mx,fmaf(R[4],my,R[5]*mz)) + t[1] - g[3*n+1];
        float pz = fmaf(R[6],mx,fmaf(R[7],my,R[8]*mz)) + t[2] - g[3*n+2];
        dis = sqrtf(fmaf(px,px,fmaf(py,py,pz*pz)));
    }
    float acc = dis;
    #pragma unroll
    for (int off = 32; off > 0; off >>= 1) acc += __shfl_down(acc, off, 64);
    __shared__ float sred[4];
    if ((tid & 63) == 0) sred[tid >> 6] = acc;
    __syncthreads();
    if (tid == 0) psum[blockIdx.x] = (sred[0] + sred[1]) + (sred[2] + sred[3]);
}

// Final reduction of 64 partial sums -> mean.
__global__ void k_final(const float* __restrict__ psum, float* __restrict__ out) {
    float v = psum[threadIdx.x];
    #pragma unroll
    for (int off = 32; off > 0; off >>= 1) v += __shfl_down(v, off, 64);
    if (threadIdx.x == 0) out[0] = v / (float)N_PTS;
}

extern "C" void kernel_launch(void* const* d_in, const int* in_sizes, int n_in,
                              void* d_out, int out_size, void* d_ws, size_t ws_size,
                              hipStream_t stream) {
    const float* R   = (const float*)d_in[0];
    const float* t   = (const float*)d_in[1];
    const float* m   = (const float*)d_in[2];
    const float* g   = (const float*)d_in[3];
    const int* midx  = (const int*)d_in[4];

    char* ws = (char*)d_ws;
    float* out = (float*)d_out;

    const size_t partial_bytes = (size_t)NGCHUNK * N_PTS * 4;   // 4 MB
    const bool use_partial = ws_size >= partial_bytes + 1024;

    if (use_partial) {
        float* partial = (float*)ws;
        float* psum    = (float*)(ws + partial_bytes);
        k_nn<false><<<dim3(NPBLK, NGCHUNK), dim3(256), 0, stream>>>(R, t, m, g, partial);
        k_finalize<false><<<dim3(N_PTS/256), dim3(256), 0, stream>>>(R, t, m, g, partial, midx, psum);
        k_final<<<dim3(1), dim3(64), 0, stream>>>(psum, out);
    } else {
        unsigned* keys = (unsigned*)ws;
        float* psum    = (float*)(ws + N_PTS * 4);
        k_init<<<dim3(N_PTS/256), dim3(256), 0, stream>>>(keys);
        k_nn<true><<<dim3(NPBLK, NGCHUNK), dim3(256), 0, stream>>>(R, t, m, g, (float*)keys);
        k_finalize<true><<<dim3(N_PTS/256), dim3(256), 0, stream>>>(R, t, m, g, (float*)keys, midx, psum);
        k_final<<<dim3(1), dim3(64), 0, stream>>>(psum, out);
    }
}